// Round 10
// baseline (36.781 us; speedup 1.0000x reference)
//
#include <hip/hip_runtime.h>

#define ALPHA 0.2f
#define BATCH 16
#define WIN 100
#define KN 128          // nodes
#define DE 200          // embed dim
#define IT 8            // i-tile per block
#define DSL 25          // d-slice per wave-pair (8 x 25 = 200)

typedef float v2f __attribute__((ext_vector_type(2)));

// Single fused kernel, NO inter-block dependency: each block (b, i-tile)
// recomputes its Rt slice in registers (redundancy 16x on the right-GEMM,
// traded for: no 2nd dispatch, no node drain, no Rt/Lt global round-trip).
// Thread (j = t&127, dh = t>>7): rt[k] = Rt[db+k][j] local, k<25.
__global__ __launch_bounds__(1024) void k_gat(
    const float* __restrict__ in, const float* __restrict__ lw,
    const float* __restrict__ lb, const float* __restrict__ aw,
    float* __restrict__ out) {
  int blk = blockIdx.x;
  int b = blk >> 4, it = blk & 15, i0 = it * IT;
  int t = threadIdx.x;
  int j = t & (KN - 1);
  int dh = t >> 7;
  int db = __builtin_amdgcn_readfirstlane(dh * DSL);

  __shared__ float Lis[DE][IT];       // [d][ii], 32B rows (broadcast reads)
  __shared__ float part[8][IT][KN];
  __shared__ float part_r[8][KN];
  __shared__ float ats[IT][132];

  // --- Phase B: Li for this block's 8 i's (block-local, as in round 6) ---
  for (int idx = t; idx < IT * DE; idx += 1024) {
    int ii = idx / DE;                // consecutive idx -> consecutive d
    int d = idx - ii * DE;
    const float* xc = in + (size_t)b * WIN * KN + i0 + ii;
    const float* lc = lw + d;
    float a = 0.f;
#pragma unroll 4
    for (int w = 0; w < WIN; ++w)
      a = fmaf(xc[w * KN], lc[w * DE], a);
    Lis[d][ii] = a;
  }

  // --- Phase A: Rt slice in registers ---
  float rt[DSL];
#pragma unroll
  for (int k = 0; k < DSL; ++k) rt[k] = 0.f;
  {
    const float* xcol = in + (size_t)b * WIN * KN + j;
    const float* lwr = lw + (size_t)WIN * DE + db;   // wave-uniform -> s_load
#pragma unroll 2
    for (int w = 0; w < WIN; ++w) {
      float x = xcol[(size_t)w * KN];                // coalesced across lanes
#pragma unroll
      for (int k = 0; k < DSL; ++k)
        rt[k] = fmaf(x, lwr[(size_t)w * DE + k], rt[k]);
    }
#pragma unroll
    for (int k = 0; k < DSL; ++k) rt[k] += lb[db + k];
  }

  __syncthreads();

  // --- Phase C: e-partials; Rt from registers, Li broadcast from LDS ---
  {
    v2f acc0 = 0.f, acc1 = 0.f, acc2 = 0.f, acc3 = 0.f;
    float racc = 0.f;
#pragma unroll 5
    for (int k = 0; k < DSL; ++k) {
      int d = db + k;
      float r = rt[k];
      float a = aw[d];                               // uniform -> s_load
      float4 L0 = *reinterpret_cast<const float4*>(&Lis[d][0]);
      float4 L1 = *reinterpret_cast<const float4*>(&Lis[d][4]);
      racc = fmaf(r, a, racc);
      v2f rv = {r, r}, av = {a, a}, z = 0.f;
      v2f p0 = (v2f){L0.x, L0.y} + rv;
      v2f p1 = (v2f){L0.z, L0.w} + rv;
      v2f p2 = (v2f){L1.x, L1.y} + rv;
      v2f p3 = (v2f){L1.z, L1.w} + rv;
      p0 = __builtin_elementwise_min(p0, z);
      p1 = __builtin_elementwise_min(p1, z);
      p2 = __builtin_elementwise_min(p2, z);
      p3 = __builtin_elementwise_min(p3, z);
      acc0 += p0 * av; acc1 += p1 * av; acc2 += p2 * av; acc3 += p3 * av;
    }
    part[dh][0][j] = acc0.x; part[dh][1][j] = acc0.y;
    part[dh][2][j] = acc1.x; part[dh][3][j] = acc1.y;
    part[dh][4][j] = acc2.x; part[dh][5][j] = acc2.y;
    part[dh][6][j] = acc3.x; part[dh][7][j] = acc3.y;
    part_r[dh][j] = racc;
  }
  __syncthreads();

  // --- softmax: wave r (r<8) owns row r; e = ra - 0.8*M (shift-invariant) ---
  {
    int wid = t >> 6;
    if (wid < IT) {
      int r = wid, l = t & 63;
      float ra0 = 0.f, ra1 = 0.f, m0 = 0.f, m1 = 0.f;
#pragma unroll
      for (int s = 0; s < 8; ++s) {
        ra0 += part_r[s][l];     ra1 += part_r[s][l + 64];
        m0  += part[s][r][l];    m1  += part[s][r][l + 64];
      }
      float e0 = fmaf(m0, -(1.f - ALPHA), ra0);
      float e1 = fmaf(m1, -(1.f - ALPHA), ra1);
      float m = fmaxf(e0, e1);
      for (int off = 32; off; off >>= 1) m = fmaxf(m, __shfl_xor(m, off));
      float p0 = __expf(e0 - m), p1 = __expf(e1 - m);
      float s2 = p0 + p1;
      for (int off = 32; off; off >>= 1) s2 += __shfl_xor(s2, off);
      float inv = 1.f / s2;
      ats[r][l] = p0 * inv;
      ats[r][l + 64] = p1 * inv;
    }
  }
  __syncthreads();

  // --- PV: thread (w, q<8): out[b][w][i0+q]; x rows from global (L1-shared) ---
  if (t < 8 * WIN) {
    int w = t >> 3, q = t & 7;
    const float* xw = in + ((size_t)b * WIN + w) * KN;
    const float* ap = &ats[q][0];
    float s = 0.f;
#pragma unroll 8
    for (int jj = 0; jj < KN; jj += 4) {
      float4 x4 = *reinterpret_cast<const float4*>(xw + jj);
      float4 aa = *reinterpret_cast<const float4*>(ap + jj);
      s = fmaf(aa.x, x4.x, s); s = fmaf(aa.y, x4.y, s);
      s = fmaf(aa.z, x4.z, s); s = fmaf(aa.w, x4.w, s);
    }
    out[((size_t)b * WIN + w) * KN + i0 + q] = 1.f / (1.f + __expf(-s));
  }
}

extern "C" void kernel_launch(void* const* d_in, const int* in_sizes, int n_in,
                              void* d_out, int out_size, void* d_ws, size_t ws_size,
                              hipStream_t stream) {
  const float* in = (const float*)d_in[0];   // (16,100,128)
  const float* lw = (const float*)d_in[1];   // (200,200)
  const float* lb = (const float*)d_in[2];   // (200,)
  const float* aw = (const float*)d_in[3];   // (200,)
  float* out = (float*)d_out;                // (16,100,128)

  k_gat<<<BATCH * 16, 1024, 0, stream>>>(in, lw, lb, aw, out);
}